// Round 5
// baseline (451.058 us; speedup 1.0000x reference)
//
#include <hip/hip_runtime.h>
#include <cstdint>
#include <cstddef>
#include <cmath>

#define D 128

typedef short bf16x8 __attribute__((ext_vector_type(8)));
typedef float f32x4 __attribute__((ext_vector_type(4)));

__device__ __forceinline__ ushort f2b(float f) {
  uint x = __float_as_uint(f);
  uint r = ((x >> 16) & 1u) + 0x7fffu;   // round-to-nearest-even
  return (ushort)((x + r) >> 16);
}
__device__ __forceinline__ float b2f(ushort u) {
  return __uint_as_float(((uint)u) << 16);
}

// global -> LDS direct DMA, 16B per lane; HW writes lane l at lds_base + l*16
__device__ __forceinline__ void gl2lds16(const void* g, void* l) {
  __builtin_amdgcn_global_load_lds(
      (__attribute__((address_space(1))) void*)const_cast<void*>(g),
      (__attribute__((address_space(3))) void*)l, 16, 0, 0);
}

// ======================= CSR build (XCD-partitioned) =======================
__global__ __launch_bounds__(256) void k_degree_p(const int* __restrict__ dst, int E,
    int* __restrict__ deg, float scale, int CE) {
  int part = blockIdx.x & 7, chunk = blockIdx.x >> 3;
  long base = (long)chunk * CE;
  for (int i = threadIdx.x; i < CE; i += 256) {
    long e = base + i;
    if (e < E) {
      int d = dst[e];
      int p = (int)((float)d * scale); if (p > 7) p = 7;
      if (p == part) atomicAdd(&deg[d], 1);
    }
  }
}

__global__ __launch_bounds__(256) void k_fill_p(const int* __restrict__ src,
    const int* __restrict__ dst, int E, int* __restrict__ cursor,
    int* __restrict__ csrc, float scale, int CE) {
  int part = blockIdx.x & 7, chunk = blockIdx.x >> 3;
  long base = (long)chunk * CE;
  for (int i = threadIdx.x; i < CE; i += 256) {
    long e = base + i;
    if (e < E) {
      int d = dst[e];
      int p = (int)((float)d * scale); if (p > 7) p = 7;
      if (p == part) {
        int s = src[e];
        int pos = atomicAdd(&cursor[d], 1);
        csrc[pos] = s;
      }
    }
  }
}

#define SCAN_T 256
#define SCAN_E 4
#define SCAN_CHUNK (SCAN_T * SCAN_E)

__global__ void k_scan_partial(const int* __restrict__ deg, int n, int* __restrict__ part) {
  __shared__ int s[SCAN_T];
  int base = blockIdx.x * SCAN_CHUNK;
  int sum = 0;
  for (int i = 0; i < SCAN_E; ++i) {
    int idx = base + (int)threadIdx.x * SCAN_E + i;
    if (idx < n) sum += deg[idx];
  }
  s[threadIdx.x] = sum; __syncthreads();
  for (int ofs = SCAN_T / 2; ofs > 0; ofs >>= 1) {
    if ((int)threadIdx.x < ofs) s[threadIdx.x] += s[threadIdx.x + ofs];
    __syncthreads();
  }
  if (threadIdx.x == 0) part[blockIdx.x] = s[0];
}

__global__ void k_scan_part_ex(int* __restrict__ part, int nb) {
  __shared__ int s[1024];
  int v = ((int)threadIdx.x < nb) ? part[threadIdx.x] : 0;
  s[threadIdx.x] = v; __syncthreads();
  for (int ofs = 1; ofs < 1024; ofs <<= 1) {
    int t = ((int)threadIdx.x >= ofs) ? s[threadIdx.x - ofs] : 0;
    __syncthreads();
    s[threadIdx.x] += t;
    __syncthreads();
  }
  if ((int)threadIdx.x < nb) part[threadIdx.x] = s[threadIdx.x] - v;  // exclusive
}

__global__ void k_scan_final(const int* __restrict__ deg, int n, const int* __restrict__ part,
                             int* __restrict__ rowptr, int* __restrict__ cursor, int E) {
  __shared__ int s[SCAN_T];
  int base = blockIdx.x * SCAN_CHUNK;
  int v[SCAN_E]; int local = 0;
  for (int i = 0; i < SCAN_E; ++i) {
    int idx = base + (int)threadIdx.x * SCAN_E + i;
    v[i] = (idx < n) ? deg[idx] : 0;
    local += v[i];
  }
  s[threadIdx.x] = local; __syncthreads();
  for (int ofs = 1; ofs < SCAN_T; ofs <<= 1) {
    int t = ((int)threadIdx.x >= ofs) ? s[threadIdx.x - ofs] : 0;
    __syncthreads();
    s[threadIdx.x] += t;
    __syncthreads();
  }
  int run = part[blockIdx.x] + s[threadIdx.x] - local;  // exclusive prefix
  for (int i = 0; i < SCAN_E; ++i) {
    int idx = base + (int)threadIdx.x * SCAN_E + i;
    if (idx < n) { rowptr[idx] = run; cursor[idx] = run; }
    run += v[i];
  }
  if (blockIdx.x == 0 && threadIdx.x == 0) rowptr[n] = E;
}

// ======================= fp32 -> bf16 convert =======================
__global__ void k_conv_bf16(const float* __restrict__ in, ushort* __restrict__ out, int n8) {
  int i = blockIdx.x * 256 + threadIdx.x;
  if (i >= n8) return;
  float4 a = ((const float4*)in)[i * 2];
  float4 b = ((const float4*)in)[i * 2 + 1];
  ushort4 o0 = {f2b(a.x), f2b(a.y), f2b(a.z), f2b(a.w)};
  ushort4 o1 = {f2b(b.x), f2b(b.y), f2b(b.z), f2b(b.w)};
  ((ushort4*)out)[i * 2] = o0;
  ((ushort4*)out)[i * 2 + 1] = o1;
}

// ======================= pack ALL weights to B-fragment order ==================
__global__ void k_pack_all(
    const float* __restrict__ Ws0, const float* __restrict__ Wn0,
    const float* __restrict__ Ws1, const float* __restrict__ Wn1,
    const float* __restrict__ Ws2, const float* __restrict__ Wn2,
    const float* __restrict__ Wp0, const float* __restrict__ Wp1,
    ushort* __restrict__ BpL0, ushort* __restrict__ BpL1, ushort* __restrict__ BpL2,
    ushort* __restrict__ BpP0, ushort* __restrict__ BpP1) {
  int o = blockIdx.x * 256 + threadIdx.x;   // total 131072
  const float *W0, *W1; ushort* out; int rel;
  if (o < 32768)       { W0 = Ws0; W1 = Wn0; out = BpL0; rel = o; }
  else if (o < 65536)  { W0 = Ws1; W1 = Wn1; out = BpL1; rel = o - 32768; }
  else if (o < 98304)  { W0 = Ws2; W1 = Wn2; out = BpL2; rel = o - 65536; }
  else if (o < 114688) { W0 = Wp0; W1 = Wp0; out = BpP0; rel = o - 98304; }
  else                 { W0 = Wp1; W1 = Wp1; out = BpP1; rel = o - 114688; }
  int j = rel & 7, lane = (rel >> 3) & 63, t = (rel >> 9) & 7, ks = rel >> 12;
  int k = ks * 32 + ((lane >> 4) * 8) + j;
  int n = t * 16 + (lane & 15);
  const float* W = (k < 128) ? W0 : W1;
  int kk = (k < 128) ? k : k - 128;
  out[rel] = f2b(W[(size_t)kk * D + n]);
}

// ======================= fused aggregate + SAGE GEMM =======================
// Block = 128 threads = 2 wave-tiles of 16 rows. Gather via global_load_lds
// on the VERIFIED m97 pattern: stage -> __syncthreads() -> ds_read (the
// compiler emits the vmcnt(0) drain before s_barrier itself; no hand-rolled
// waitcnt interleave). Per slot s (block-uniform bound = block-max degree,
// capped 16): each wave issues 4 global_load_lds that stage its 16 nodes'
// slot-s neighbor rows (4KB) into its wave slab; barrier; accumulate from
// LDS with {0,1} weight for dummy slots (which load row 0, L1-hot); barrier.
// Zero data-VGPR staging -> no register-cluster fight (rounds 1-3), LDS only
// 8.7KB/block (slab reused for smean after the last barrier) -> high
// occupancy carries the latency hiding.
#define SMS 136
__global__ __launch_bounds__(128, 6) void k_sage_fused(
    const ushort* __restrict__ A, const int* __restrict__ rowptr,
    const int* __restrict__ csrc, const ushort* __restrict__ Bp,
    const float* __restrict__ bias, ushort* __restrict__ out, int N, int do_relu) {
  __shared__ __align__(256) ushort lbuf[2][2176];   // 4352 B per wave slab
  __shared__ int mdx[2];
  int tid = threadIdx.x, wave = tid >> 6, lane = tid & 63;
  int m = lane & 15, kg = lane >> 4;        // MFMA roles
  int g = kg, sub = m;                      // gather roles: 4 groups of 16
  int gb = g << 4;                          // group base lane
  int row0 = (blockIdx.x * 2 + wave) * 16;  // this wave's 16-row tile
  uint slice16 = (uint)(sub * 16);          // byte offset of this lane's 16B slice
  char* lw = (char*)&lbuf[wave][0];         // wave slab (staging 4KB; smean after)

  // ---- phase A: rowptr (5 per group) + degree bookkeeping ----
  int node0 = row0 + g * 4;
  int rpv = 0;
  if (sub < 5) { int ix = node0 + sub; if (ix > N) ix = N; rpv = rowptr[ix]; }
  int beg[4], dgf[4], dd[4];
  #pragma unroll
  for (int j = 0; j < 4; ++j) {
    beg[j] = __shfl(rpv, gb + j);
    int endj = __shfl(rpv, gb + j + 1);
    dgf[j] = endj - beg[j];
    dd[j] = dgf[j] < 16 ? dgf[j] : 16;
  }

  // ---- edge-index quad: lane l holds node l>>2 (relative), slots (l&3)*4+0..3
  int i0 = 0, i1 = 0, i2 = 0, i3 = 0;
  {
    int nl = lane >> 2;
    int hb = ((nl >> 2) << 4) + (nl & 3);     // lane holding rowptr[node nl]
    int bn = __shfl(rpv, hb);
    int dn = __shfl(rpv, hb + 1) - bn;
    int s0 = (lane & 3) << 2;
    if (s0 + 0 < dn) i0 = csrc[bn + s0 + 0];
    if (s0 + 1 < dn) i1 = csrc[bn + s0 + 1];
    if (s0 + 2 < dn) i2 = csrc[bn + s0 + 2];
    if (s0 + 3 < dn) i3 = csrc[bn + s0 + 3];
  }

  // ---- block-uniform slot count (block-max of capped degrees) ----
  int md = dd[0];
  if (dd[1] > md) md = dd[1];
  if (dd[2] > md) md = dd[2];
  if (dd[3] > md) md = dd[3];
  {
    int t = __shfl_xor(md, 16); if (t > md) md = t;
    t = __shfl_xor(md, 32); if (t > md) md = t;
  }
  if (lane == 0) mdx[wave] = md;
  __syncthreads();
  int mdb = mdx[0] > mdx[1] ? mdx[0] : mdx[1];

  float f[4][8];
  #pragma unroll
  for (int j = 0; j < 4; ++j)
    #pragma unroll
    for (int q = 0; q < 8; ++q) f[j][q] = 0.f;

  // ---- slot loop: stage -> barrier -> accumulate -> barrier ----
  #pragma unroll 1
  for (int s = 0; s < mdb; ++s) {
    {  // stage slot s: 4 x global_load_lds; instr q covers relative rows q*4..q*4+3
      int val = (s & 2) ? ((s & 1) ? i3 : i2) : ((s & 1) ? i1 : i0);
      int sb = ((lane >> 4) << 2) + (s >> 2);
      #pragma unroll
      for (int q = 0; q < 4; ++q) {
        int idx = __shfl(val, (q << 4) + sb);
        gl2lds16((const char*)A + (((uint)idx) << 8) + slice16, lw + (q << 10));
      }
    }
    __syncthreads();   // compiler-inserted vmcnt(0) drain + barrier (m97 path)
    const char* rb = lw + g * 1024 + slice16;
    #pragma unroll
    for (int j = 0; j < 4; ++j) {
      bf16x8 v = *(const bf16x8*)(rb + j * 256);
      float w = (s < dd[j]) ? 1.0f : 0.0f;
      #pragma unroll
      for (int q = 0; q < 8; ++q) f[j][q] += w * b2f((ushort)v[q]);
    }
    __syncthreads();   // all reads done before next slot's DMA overwrites
  }

  // rare deg>16 tail (plain vector loads)
  #pragma unroll
  for (int j = 0; j < 4; ++j) {
    int endj = beg[j] + dgf[j];
    for (int i = beg[j] + 16; i < endj; ++i) {
      int si = csrc[i];
      bf16x8 v = *(const bf16x8*)((const char*)A + (((uint)si) << 8) + slice16);
      #pragma unroll
      for (int q = 0; q < 8; ++q) f[j][q] += b2f((ushort)v[q]);
    }
  }

  // write means into the wave slab (staging fully consumed; slab is
  // wave-private so only a wave-local LDS handoff is needed)
  ushort* smw = (ushort*)lw;
  #pragma unroll
  for (int j = 0; j < 4; ++j) {
    float inv = (dgf[j] > 0) ? (1.0f / (float)dgf[j]) : 0.0f;
    bf16x8 o;
    #pragma unroll
    for (int q = 0; q < 8; ++q) o[q] = (short)f2b(f[j][q] * inv);
    *(bf16x8*)&smw[(g * 4 + j) * SMS + sub * 8] = o;
  }
  asm volatile("s_waitcnt lgkmcnt(0)" ::: "memory");
  __builtin_amdgcn_sched_barrier(0);

  // ---- MFMA phase ----
  int ar = row0 + m; if (ar >= N) ar = N - 1;   // clamp reads; stores guarded
  const ushort* a_self = A + (size_t)ar * D + kg * 8;
  f32x4 acc[8];
  #pragma unroll
  for (int t = 0; t < 8; ++t) acc[t] = f32x4{0.f, 0.f, 0.f, 0.f};
  #pragma unroll
  for (int ks = 0; ks < 8; ++ks) {
    bf16x8 af = (ks < 4) ? *(const bf16x8*)(a_self + ks * 32)
                         : *(const bf16x8*)&smw[m * SMS + (ks - 4) * 32 + kg * 8];
    const ushort* bb = Bp + (size_t)ks * 4096 + lane * 8;
    #pragma unroll
    for (int t = 0; t < 8; ++t)
      acc[t] = __builtin_amdgcn_mfma_f32_16x16x32_bf16(af, *(const bf16x8*)(bb + t * 512), acc[t], 0, 0, 0);
  }
  #pragma unroll
  for (int t = 0; t < 8; ++t) {
    int c = t * 16 + m;
    float bv = bias[c];
    #pragma unroll
    for (int i = 0; i < 4; ++i) {
      int r = row0 + kg * 4 + i;
      float v = acc[t][i] + bv;
      if (do_relu) v = fmaxf(v, 0.f);
      if (r < N) out[(size_t)r * D + c] = f2b(v);
    }
  }
}

// ======================= fused predictor MLP (MFMA, pos+neg merged) ============
__global__ __launch_bounds__(256) void k_predict_mfma(
    const ushort* __restrict__ h,
    const int* __restrict__ ps, const int* __restrict__ pd,
    const int* __restrict__ ns, const int* __restrict__ nd,
    const ushort* __restrict__ Bp0, const float* __restrict__ bp0,
    const ushort* __restrict__ Bp1, const float* __restrict__ bp1,
    const float* __restrict__ Wp2, const float* __restrict__ bp2,
    float* __restrict__ outp, int P, int pb) {
  __shared__ __align__(16) ushort z1p[4][2048];  // per-wave A-frag-packed z1
  int bi = blockIdx.x;
  const int* sidx; const int* didx; float* op;
  if (bi >= pb) { sidx = ns; didx = nd; op = outp + P; bi -= pb; }
  else          { sidx = ps; didx = pd; op = outp; }
  int tid = threadIdx.x;
  int wave = tid >> 6, lane = tid & 63;
  int m = lane & 15, kg = lane >> 4;
  int pair0 = bi * 64 + wave * 16;
  int prow = pair0 + m; int pr = (prow < P) ? prow : P - 1;
  int si = sidx[pr], di = didx[pr];
  const ushort* hs = h + (size_t)si * D + kg * 8;
  const ushort* hd = h + (size_t)di * D + kg * 8;
  f32x4 acc[8];
  #pragma unroll
  for (int t = 0; t < 8; ++t) acc[t] = f32x4{0.f, 0.f, 0.f, 0.f};
  // ---- GEMM1: z = hs*hd ; acc = z @ Wp0 ----
  #pragma unroll
  for (int ks = 0; ks < 4; ++ks) {
    bf16x8 as8 = *(const bf16x8*)(hs + ks * 32);
    bf16x8 ad8 = *(const bf16x8*)(hd + ks * 32);
    bf16x8 af;
    #pragma unroll
    for (int j = 0; j < 8; ++j) {
      float p = b2f((ushort)as8[j]) * b2f((ushort)ad8[j]);
      af[j] = (short)f2b(p);
    }
    const ushort* bb = Bp0 + (size_t)ks * 4096 + lane * 8;
    #pragma unroll
    for (int t = 0; t < 8; ++t)
      acc[t] = __builtin_amdgcn_mfma_f32_16x16x32_bf16(af, *(const bf16x8*)(bb + t * 512), acc[t], 0, 0, 0);
  }
  // ---- epilogue1: relu(acc + bp0) -> LDS in GEMM2 A-fragment packed order ----
  ushort* zp = &z1p[wave][0];
  #pragma unroll
  for (int t = 0; t < 8; ++t) {
    int c = t * 16 + m;
    float bv = bp0[c];
    int ks2 = c >> 5, kg2 = (c >> 3) & 3, j2 = c & 7;
    #pragma unroll
    for (int i = 0; i < 4; ++i) {
      float v = fmaxf(acc[t][i] + bv, 0.f);
      int l2 = kg2 * 16 + kg * 4 + i;     // consumer lane
      zp[(ks2 * 64 + l2) * 8 + j2] = f2b(v);
    }
  }
  __syncthreads();
  // ---- GEMM2: acc = z1 @ Wp1 ----
  #pragma unroll
  for (int t = 0; t < 8; ++t) acc[t] = f32x4{0.f, 0.f, 0.f, 0.f};
  #pragma unroll
  for (int ks = 0; ks < 4; ++ks) {
    bf16x8 af = *(const bf16x8*)(zp + (ks * 64 + lane) * 8);
    const ushort* bb = Bp1 + (size_t)ks * 4096 + lane * 8;
    #pragma unroll
    for (int t = 0; t < 8; ++t)
      acc[t] = __builtin_amdgcn_mfma_f32_16x16x32_bf16(af, *(const bf16x8*)(bb + t * 512), acc[t], 0, 0, 0);
  }
  // ---- final: z2 = relu(acc + bp1); logits = z2 @ Wp2 + bp2; sigmoid ----
  float p0[4] = {0.f, 0.f, 0.f, 0.f}, p1[4] = {0.f, 0.f, 0.f, 0.f};
  #pragma unroll
  for (int t = 0; t < 8; ++t) {
    int c = t * 16 + m;
    float bv = bp1[c];
    float wa = Wp2[(size_t)c * 2], wb = Wp2[(size_t)c * 2 + 1];
    #pragma unroll
    for (int i = 0; i < 4; ++i) {
      float z = fmaxf(acc[t][i] + bv, 0.f);
      p0[i] += z * wa;
      p1[i] += z * wb;
    }
  }
  #pragma unroll
  for (int msk = 1; msk <= 8; msk <<= 1) {
    #pragma unroll
    for (int i = 0; i < 4; ++i) {
      p0[i] += __shfl_xor(p0[i], msk);
      p1[i] += __shfl_xor(p1[i], msk);
    }
  }
  if (m == 0) {
    float c0 = bp2[0], c1 = bp2[1];
    #pragma unroll
    for (int i = 0; i < 4; ++i) {
      int r = pair0 + kg * 4 + i;
      if (r < P) {
        float l0 = p0[i] + c0, l1 = p1[i] + c1;
        op[r] = 1.0f / (1.0f + expf(l0 - l1));
      }
    }
  }
}

// ======================= launch =======================
extern "C" void kernel_launch(void* const* d_in, const int* in_sizes, int n_in,
                              void* d_out, int out_size, void* d_ws, size_t ws_size,
                              hipStream_t stream) {
  const float* x       = (const float*)d_in[0];
  const int*   src     = (const int*)d_in[1];
  const int*   dst     = (const int*)d_in[2];
  const int*   pos_src = (const int*)d_in[3];
  const int*   pos_dst = (const int*)d_in[4];
  const int*   neg_src = (const int*)d_in[5];
  const int*   neg_dst = (const int*)d_in[6];
  const float* Ws0 = (const float*)d_in[7],  *Wn0 = (const float*)d_in[8],  *b0 = (const float*)d_in[9];
  const float* Ws1 = (const float*)d_in[10], *Wn1 = (const float*)d_in[11], *b1 = (const float*)d_in[12];
  const float* Ws2 = (const float*)d_in[13], *Wn2 = (const float*)d_in[14], *b2 = (const float*)d_in[15];
  const float* Wp0 = (const float*)d_in[16], *bp0 = (const float*)d_in[17];
  const float* Wp1 = (const float*)d_in[18], *bp1 = (const float*)d_in[19];
  const float* Wp2 = (const float*)d_in[20], *bp2 = (const float*)d_in[21];
  const int N = in_sizes[0] / D;
  const int E = in_sizes[1];
  const int P = in_sizes[3];
  float* outp = (float*)d_out;

  char* ws = (char*)d_ws;
  size_t off = 0;
  auto alloc = [&](size_t bytes) -> void* {
    void* p = ws + off;
    off += (bytes + 255) & ~(size_t)255;
    return p;
  };
  ushort* xb    = (ushort*)alloc((size_t)N * D * 2);
  ushort* h1    = (ushort*)alloc((size_t)N * D * 2);
  ushort* h2    = (ushort*)alloc((size_t)N * D * 2);
  ushort* BpL0  = (ushort*)alloc(256 * D * 2);
  ushort* BpL1  = (ushort*)alloc(256 * D * 2);
  ushort* BpL2  = (ushort*)alloc(256 * D * 2);
  ushort* BpP0  = (ushort*)alloc(128 * D * 2);
  ushort* BpP1  = (ushort*)alloc(128 * D * 2);
  int*    deg    = (int*)alloc((size_t)N * 4);
  int*    rowptr = (int*)alloc((size_t)(N + 1) * 4);
  int*    cursor = (int*)alloc((size_t)N * 4);
  int*    part   = (int*)alloc(4096);
  int*    csrc   = (int*)alloc((size_t)E * 4);
  (void)ws_size; (void)n_in; (void)out_size;

  const float pscale = 8.0f / (float)N;
  const int CB = 96;                           // blocks per part
  const int CE = (E + CB - 1) / CB;            // edges per chunk

  // --- CSR build (XCD-partitioned) ---
  hipMemsetAsync(deg, 0, (size_t)N * 4, stream);
  k_degree_p<<<8 * CB, 256, 0, stream>>>(dst, E, deg, pscale, CE);
  int nb = (N + SCAN_CHUNK - 1) / SCAN_CHUNK;
  k_scan_partial<<<nb, SCAN_T, 0, stream>>>(deg, N, part);
  k_scan_part_ex<<<1, 1024, 0, stream>>>(part, nb);
  k_scan_final<<<nb, SCAN_T, 0, stream>>>(deg, N, part, rowptr, cursor, E);
  k_fill_p<<<8 * CB, 256, 0, stream>>>(src, dst, E, cursor, csrc, pscale, CE);

  // --- conversions / weight packing ---
  int n8 = N * D / 8;
  k_conv_bf16<<<(n8 + 255) / 256, 256, 0, stream>>>(x, xb, n8);
  k_pack_all<<<512, 256, 0, stream>>>(Ws0, Wn0, Ws1, Wn1, Ws2, Wn2, Wp0, Wp1,
                                      BpL0, BpL1, BpL2, BpP0, BpP1);

  int gemb = (N + 31) / 32;
  k_sage_fused<<<gemb, 128, 0, stream>>>(xb, rowptr, csrc, BpL0, b0, h1, N, 1);
  k_sage_fused<<<gemb, 128, 0, stream>>>(h1, rowptr, csrc, BpL1, b1, h2, N, 1);
  k_sage_fused<<<gemb, 128, 0, stream>>>(h2, rowptr, csrc, BpL2, b2, xb, N, 0);

  int pb = (P + 63) / 64;
  k_predict_mfma<<<2 * pb, 256, 0, stream>>>(xb, pos_src, pos_dst, neg_src, neg_dst,
                                             BpP0, bp0, BpP1, bp1, Wp2, bp2, outp, P, pb);
}

// Round 6
// 441.620 us; speedup vs baseline: 1.0214x; 1.0214x over previous
//
#include <hip/hip_runtime.h>
#include <cstdint>
#include <cstddef>
#include <cmath>

#define D 128

typedef short bf16x8 __attribute__((ext_vector_type(8)));
typedef float f32x4 __attribute__((ext_vector_type(4)));

__device__ __forceinline__ ushort f2b(float f) {
  uint x = __float_as_uint(f);
  uint r = ((x >> 16) & 1u) + 0x7fffu;   // round-to-nearest-even
  return (ushort)((x + r) >> 16);
}
__device__ __forceinline__ float b2f(ushort u) {
  return __uint_as_float(((uint)u) << 16);
}

// ======================= CSR build (XCD-partitioned) =======================
__global__ __launch_bounds__(256) void k_degree_p(const int* __restrict__ dst, int E,
    int* __restrict__ deg, float scale, int CE) {
  int part = blockIdx.x & 7, chunk = blockIdx.x >> 3;
  long base = (long)chunk * CE;
  for (int i = threadIdx.x; i < CE; i += 256) {
    long e = base + i;
    if (e < E) {
      int d = dst[e];
      int p = (int)((float)d * scale); if (p > 7) p = 7;
      if (p == part) atomicAdd(&deg[d], 1);
    }
  }
}

__global__ __launch_bounds__(256) void k_fill_p(const int* __restrict__ src,
    const int* __restrict__ dst, int E, int* __restrict__ cursor,
    int* __restrict__ csrc, float scale, int CE) {
  int part = blockIdx.x & 7, chunk = blockIdx.x >> 3;
  long base = (long)chunk * CE;
  for (int i = threadIdx.x; i < CE; i += 256) {
    long e = base + i;
    if (e < E) {
      int d = dst[e];
      int p = (int)((float)d * scale); if (p > 7) p = 7;
      if (p == part) {
        int s = src[e];
        int pos = atomicAdd(&cursor[d], 1);
        csrc[pos] = s;
      }
    }
  }
}

#define SCAN_T 256
#define SCAN_E 4
#define SCAN_CHUNK (SCAN_T * SCAN_E)

__global__ void k_scan_partial(const int* __restrict__ deg, int n, int* __restrict__ part) {
  __shared__ int s[SCAN_T];
  int base = blockIdx.x * SCAN_CHUNK;
  int sum = 0;
  for (int i = 0; i < SCAN_E; ++i) {
    int idx = base + (int)threadIdx.x * SCAN_E + i;
    if (idx < n) sum += deg[idx];
  }
  s[threadIdx.x] = sum; __syncthreads();
  for (int ofs = SCAN_T / 2; ofs > 0; ofs >>= 1) {
    if ((int)threadIdx.x < ofs) s[threadIdx.x] += s[threadIdx.x + ofs];
    __syncthreads();
  }
  if (threadIdx.x == 0) part[blockIdx.x] = s[0];
}

__global__ void k_scan_part_ex(int* __restrict__ part, int nb) {
  __shared__ int s[1024];
  int v = ((int)threadIdx.x < nb) ? part[threadIdx.x] : 0;
  s[threadIdx.x] = v; __syncthreads();
  for (int ofs = 1; ofs < 1024; ofs <<= 1) {
    int t = ((int)threadIdx.x >= ofs) ? s[threadIdx.x - ofs] : 0;
    __syncthreads();
    s[threadIdx.x] += t;
    __syncthreads();
  }
  if ((int)threadIdx.x < nb) part[threadIdx.x] = s[threadIdx.x] - v;  // exclusive
}

__global__ void k_scan_final(const int* __restrict__ deg, int n, const int* __restrict__ part,
                             int* __restrict__ rowptr, int* __restrict__ cursor, int E) {
  __shared__ int s[SCAN_T];
  int base = blockIdx.x * SCAN_CHUNK;
  int v[SCAN_E]; int local = 0;
  for (int i = 0; i < SCAN_E; ++i) {
    int idx = base + (int)threadIdx.x * SCAN_E + i;
    v[i] = (idx < n) ? deg[idx] : 0;
    local += v[i];
  }
  s[threadIdx.x] = local; __syncthreads();
  for (int ofs = 1; ofs < SCAN_T; ofs <<= 1) {
    int t = ((int)threadIdx.x >= ofs) ? s[threadIdx.x - ofs] : 0;
    __syncthreads();
    s[threadIdx.x] += t;
    __syncthreads();
  }
  int run = part[blockIdx.x] + s[threadIdx.x] - local;  // exclusive prefix
  for (int i = 0; i < SCAN_E; ++i) {
    int idx = base + (int)threadIdx.x * SCAN_E + i;
    if (idx < n) { rowptr[idx] = run; cursor[idx] = run; }
    run += v[i];
  }
  if (blockIdx.x == 0 && threadIdx.x == 0) rowptr[n] = E;
}

// ============== fused fp32->bf16 convert + weight pack (one launch) ==========
__global__ void k_conv_pack(const float* __restrict__ in, ushort* __restrict__ out, int n8,
    int cb,
    const float* __restrict__ Ws0, const float* __restrict__ Wn0,
    const float* __restrict__ Ws1, const float* __restrict__ Wn1,
    const float* __restrict__ Ws2, const float* __restrict__ Wn2,
    const float* __restrict__ Wp0, const float* __restrict__ Wp1,
    ushort* __restrict__ BpL0, ushort* __restrict__ BpL1, ushort* __restrict__ BpL2,
    ushort* __restrict__ BpP0, ushort* __restrict__ BpP1) {
  int b = blockIdx.x;
  if (b < cb) {
    int i = b * 256 + threadIdx.x;
    if (i >= n8) return;
    float4 a = ((const float4*)in)[i * 2];
    float4 c = ((const float4*)in)[i * 2 + 1];
    ushort4 o0 = {f2b(a.x), f2b(a.y), f2b(a.z), f2b(a.w)};
    ushort4 o1 = {f2b(c.x), f2b(c.y), f2b(c.z), f2b(c.w)};
    ((ushort4*)out)[i * 2] = o0;
    ((ushort4*)out)[i * 2 + 1] = o1;
    return;
  }
  int o = (b - cb) * 256 + threadIdx.x;   // total 131072
  const float *W0, *W1; ushort* outp; int rel;
  if (o < 32768)       { W0 = Ws0; W1 = Wn0; outp = BpL0; rel = o; }
  else if (o < 65536)  { W0 = Ws1; W1 = Wn1; outp = BpL1; rel = o - 32768; }
  else if (o < 98304)  { W0 = Ws2; W1 = Wn2; outp = BpL2; rel = o - 65536; }
  else if (o < 114688) { W0 = Wp0; W1 = Wp0; outp = BpP0; rel = o - 98304; }
  else                 { W0 = Wp1; W1 = Wp1; outp = BpP1; rel = o - 114688; }
  int j = rel & 7, lane = (rel >> 3) & 63, t = (rel >> 9) & 7, ks = rel >> 12;
  int k = ks * 32 + ((lane >> 4) * 8) + j;
  int n = t * 16 + (lane & 15);
  const float* W = (k < 128) ? W0 : W1;
  int kk = (k < 128) ? k : k - 128;
  outp[rel] = f2b(W[(size_t)kk * D + n]);
}

// ======================= fused aggregate + SAGE GEMM =======================
// r2 structure (best measured: 65us) + clamped prefetch shuffle (r3 fix).
// Block = 128 threads = 2 INDEPENDENT wave-tiles of 16 rows. 4 gather groups
// x 16 lanes per wave; unroll-4 unconditional 16-load clusters; next-iter
// offset shuffles issued between loads and accumulate (DS latency hides
// under VMEM); range guard folded into fmac weight. Shuffle lane clamped to
// 15 so dummy prefetch slots resolve to edge-15's index (= row 0 for
// deg<16 nodes, L1-hot) -- no garbage fabric traffic (we are at the random-
// gather BW ceiling; wasted bytes cost real time). No keep-alive asm
// (r3: +12 VGPR, no depth gain). Waves decoupled: smean slab is wave-local.
#define SMS 136
__global__ __launch_bounds__(128, 4) void k_sage_fused(
    const ushort* __restrict__ A, const int* __restrict__ rowptr,
    const int* __restrict__ csrc, const ushort* __restrict__ Bp,
    const float* __restrict__ bias, ushort* __restrict__ out, int N, int do_relu) {
  __shared__ __align__(16) ushort smean[2][16][SMS];   // 8704 B
  int tid = threadIdx.x, wave = tid >> 6, lane = tid & 63;
  int m = lane & 15, kg = lane >> 4;        // MFMA roles
  int g = kg, sub = m;                      // gather roles: 4 groups of 16
  int gb = g << 4;                          // group base lane
  int row0 = (blockIdx.x * 2 + wave) * 16;  // this wave's 16-row tile
  uint hbo = (uint)(sub * 16);              // byte offset of this lane's 16B slice

  // ---- phase A: rowptr + edge-index prefetch ----
  int node0 = row0 + g * 4;
  int rpv = 0;
  if (sub < 5) { int ix = node0 + sub; if (ix > N) ix = N; rpv = rowptr[ix]; }
  int beg[4], dgf[4], dd[4];
  #pragma unroll
  for (int j = 0; j < 4; ++j) {
    beg[j] = __shfl(rpv, gb + j);
    int endj = __shfl(rpv, gb + j + 1);
    dgf[j] = endj - beg[j];
    dd[j] = dgf[j] < 16 ? dgf[j] : 16;
  }
  int idxv[4];
  #pragma unroll
  for (int j = 0; j < 4; ++j) {
    int i = beg[j] + sub;
    idxv[j] = (sub < dgf[j]) ? csrc[i] : 0;
  }

  // ---- phase B: unroll-4 gather, unconditional 16-load clusters ----
  float f[4][8];
  #pragma unroll
  for (int j = 0; j < 4; ++j)
    #pragma unroll
    for (int q = 0; q < 8; ++q) f[j][q] = 0.f;

  int maxdd = dd[0];
  if (dd[1] > maxdd) maxdd = dd[1];
  if (dd[2] > maxdd) maxdd = dd[2];
  if (dd[3] > maxdd) maxdd = dd[3];

  // preamble: byte offsets for edges 0..3 of each node
  uint off[4][4];
  #pragma unroll
  for (int j = 0; j < 4; ++j)
    #pragma unroll
    for (int k = 0; k < 4; ++k)
      off[j][k] = hbo + ((uint)__shfl(idxv[j], gb + k) << 8);

  #pragma unroll 1
  for (int e = 0; e < maxdd; e += 4) {
    // 16-load cluster (straight-line, no guards)
    bf16x8 r[4][4];
    #pragma unroll
    for (int j = 0; j < 4; ++j)
      #pragma unroll
      for (int k = 0; k < 4; ++k)
        r[j][k] = *(const bf16x8*)((const char*)A + off[j][k]);
    __builtin_amdgcn_sched_barrier(0);
    // next-iter offsets hide under VMEM latency; shuffle lane clamped to 15
    // so overrun slots read edge-15's index (= 0 for deg<16 -> hot row 0)
    #pragma unroll
    for (int j = 0; j < 4; ++j)
      #pragma unroll
      for (int k = 0; k < 4; ++k) {
        int sl = e + 4 + k; sl = (sl > 15) ? 15 : sl;
        off[j][k] = hbo + ((uint)__shfl(idxv[j], gb + sl) << 8);
      }
    __builtin_amdgcn_sched_barrier(0);
    // branchless guarded accumulate: w in {0,1} folded into fmac
    #pragma unroll
    for (int j = 0; j < 4; ++j) {
      #pragma unroll
      for (int k = 0; k < 4; ++k) {
        float w = (e + k < dd[j]) ? 1.0f : 0.0f;
        #pragma unroll
        for (int q = 0; q < 8; ++q) f[j][q] += w * b2f((ushort)r[j][k][q]);
      }
    }
  }
  // rare deg>16 tail
  #pragma unroll
  for (int j = 0; j < 4; ++j) {
    int endj = beg[j] + dgf[j];
    for (int i = beg[j] + 16; i < endj; ++i) {
      int s = csrc[i];
      bf16x8 v = *(const bf16x8*)((const char*)A + (hbo + ((uint)s << 8)));
      #pragma unroll
      for (int q = 0; q < 8; ++q) f[j][q] += b2f((ushort)v[q]);
    }
  }
  // write means to this wave's LDS slab
  #pragma unroll
  for (int j = 0; j < 4; ++j) {
    float inv = (dgf[j] > 0) ? (1.0f / (float)dgf[j]) : 0.0f;
    bf16x8 o;
    #pragma unroll
    for (int q = 0; q < 8; ++q) o[q] = (short)f2b(f[j][q] * inv);
    *(bf16x8*)&smean[wave][g * 4 + j][sub * 8] = o;
  }
  // wave-local handoff: smean slab is written and read by THIS wave only.
  asm volatile("s_waitcnt lgkmcnt(0)" ::: "memory");
  __builtin_amdgcn_sched_barrier(0);

  // ---- MFMA phase ----
  int ar = row0 + m; if (ar >= N) ar = N - 1;   // clamp reads; stores guarded
  const ushort* a_self = A + (size_t)ar * D + kg * 8;
  f32x4 acc[8];
  #pragma unroll
  for (int t = 0; t < 8; ++t) acc[t] = f32x4{0.f, 0.f, 0.f, 0.f};
  #pragma unroll
  for (int ks = 0; ks < 8; ++ks) {
    bf16x8 af = (ks < 4) ? *(const bf16x8*)(a_self + ks * 32)
                         : *(const bf16x8*)&smean[wave][m][(ks - 4) * 32 + kg * 8];
    const ushort* bb = Bp + (size_t)ks * 4096 + lane * 8;
    #pragma unroll
    for (int t = 0; t < 8; ++t)
      acc[t] = __builtin_amdgcn_mfma_f32_16x16x32_bf16(af, *(const bf16x8*)(bb + t * 512), acc[t], 0, 0, 0);
  }
  #pragma unroll
  for (int t = 0; t < 8; ++t) {
    int c = t * 16 + m;
    float bv = bias[c];
    #pragma unroll
    for (int i = 0; i < 4; ++i) {
      int r = row0 + kg * 4 + i;
      float v = acc[t][i] + bv;
      if (do_relu) v = fmaxf(v, 0.f);
      if (r < N) out[(size_t)r * D + c] = f2b(v);
    }
  }
}

// ======================= fused predictor MLP (MFMA, pos+neg merged) ============
// z1p slab is WAVE-private (each wave writes and reads only z1p[wave]), so
// the GEMM1->GEMM2 handoff needs only a wave-local lgkmcnt(0), not a block
// barrier -- the 4 waves run fully decoupled.
__global__ __launch_bounds__(256) void k_predict_mfma(
    const ushort* __restrict__ h,
    const int* __restrict__ ps, const int* __restrict__ pd,
    const int* __restrict__ ns, const int* __restrict__ nd,
    const ushort* __restrict__ Bp0, const float* __restrict__ bp0,
    const ushort* __restrict__ Bp1, const float* __restrict__ bp1,
    const float* __restrict__ Wp2, const float* __restrict__ bp2,
    float* __restrict__ outp, int P, int pb) {
  __shared__ __align__(16) ushort z1p[4][2048];  // per-wave A-frag-packed z1
  int bi = blockIdx.x;
  const int* sidx; const int* didx; float* op;
  if (bi >= pb) { sidx = ns; didx = nd; op = outp + P; bi -= pb; }
  else          { sidx = ps; didx = pd; op = outp; }
  int tid = threadIdx.x;
  int wave = tid >> 6, lane = tid & 63;
  int m = lane & 15, kg = lane >> 4;
  int pair0 = bi * 64 + wave * 16;
  int prow = pair0 + m; int pr = (prow < P) ? prow : P - 1;
  int si = sidx[pr], di = didx[pr];
  const ushort* hs = h + (size_t)si * D + kg * 8;
  const ushort* hd = h + (size_t)di * D + kg * 8;
  f32x4 acc[8];
  #pragma unroll
  for (int t = 0; t < 8; ++t) acc[t] = f32x4{0.f, 0.f, 0.f, 0.f};
  // ---- GEMM1: z = hs*hd ; acc = z @ Wp0 ----
  #pragma unroll
  for (int ks = 0; ks < 4; ++ks) {
    bf16x8 as8 = *(const bf16x8*)(hs + ks * 32);
    bf16x8 ad8 = *(const bf16x8*)(hd + ks * 32);
    bf16x8 af;
    #pragma unroll
    for (int j = 0; j < 8; ++j) {
      float p = b2f((ushort)as8[j]) * b2f((ushort)ad8[j]);
      af[j] = (short)f2b(p);
    }
    const ushort* bb = Bp0 + (size_t)ks * 4096 + lane * 8;
    #pragma unroll
    for (int t = 0; t < 8; ++t)
      acc[t] = __builtin_amdgcn_mfma_f32_16x16x32_bf16(af, *(const bf16x8*)(bb + t * 512), acc[t], 0, 0, 0);
  }
  // ---- epilogue1: relu(acc + bp0) -> LDS in GEMM2 A-fragment packed order ----
  ushort* zp = &z1p[wave][0];
  #pragma unroll
  for (int t = 0; t < 8; ++t) {
    int c = t * 16 + m;
    float bv = bp0[c];
    int ks2 = c >> 5, kg2 = (c >> 3) & 3, j2 = c & 7;
    #pragma unroll
    for (int i = 0; i < 4; ++i) {
      float v = fmaxf(acc[t][i] + bv, 0.f);
      int l2 = kg2 * 16 + kg * 4 + i;     // consumer lane
      zp[(ks2 * 64 + l2) * 8 + j2] = f2b(v);
    }
  }
  // wave-local handoff (slab written and read by THIS wave only)
  asm volatile("s_waitcnt lgkmcnt(0)" ::: "memory");
  __builtin_amdgcn_sched_barrier(0);
  // ---- GEMM2: acc = z1 @ Wp1 ----
  #pragma unroll
  for (int t = 0; t < 8; ++t) acc[t] = f32x4{0.f, 0.f, 0.f, 0.f};
  #pragma unroll
  for (int ks = 0; ks < 4; ++ks) {
    bf16x8 af = *(const bf16x8*)(zp + (ks * 64 + lane) * 8);
    const ushort* bb = Bp1 + (size_t)ks * 4096 + lane * 8;
    #pragma unroll
    for (int t = 0; t < 8; ++t)
      acc[t] = __builtin_amdgcn_mfma_f32_16x16x32_bf16(af, *(const bf16x8*)(bb + t * 512), acc[t], 0, 0, 0);
  }
  // ---- final: z2 = relu(acc + bp1); logits = z2 @ Wp2 + bp2; sigmoid ----
  float p0[4] = {0.f, 0.f, 0.f, 0.f}, p1[4] = {0.f, 0.f, 0.f, 0.f};
  #pragma unroll
  for (int t = 0; t < 8; ++t) {
    int c = t * 16 + m;
    float bv = bp1[c];
    float wa = Wp2[(size_t)c * 2], wb = Wp2[(size_t)c * 2 + 1];
    #pragma unroll
    for (int i = 0; i < 4; ++i) {
      float z = fmaxf(acc[t][i] + bv, 0.f);
      p0[i] += z * wa;
      p1[i] += z * wb;
    }
  }
  #pragma unroll
  for (int msk = 1; msk <= 8; msk <<= 1) {
    #pragma unroll
    for (int i = 0; i < 4; ++i) {
      p0[i] += __shfl_xor(p0[i], msk);
      p1[i] += __shfl_xor(p1[i], msk);
    }
  }
  if (m == 0) {
    float c0 = bp2[0], c1 = bp2[1];
    #pragma unroll
    for (int i = 0; i < 4; ++i) {
      int r = pair0 + kg * 4 + i;
      if (r < P) {
        float l0 = p0[i] + c0, l1 = p1[i] + c1;
        op[r] = 1.0f / (1.0f + expf(l0 - l1));
      }
    }
  }
}

// ======================= launch =======================
extern "C" void kernel_launch(void* const* d_in, const int* in_sizes, int n_in,
                              void* d_out, int out_size, void* d_ws, size_t ws_size,
                              hipStream_t stream) {
  const float* x       = (const float*)d_in[0];
  const int*   src     = (const int*)d_in[1];
  const int*   dst     = (const int*)d_in[2];
  const int*   pos_src = (const int*)d_in[3];
  const int*   pos_dst = (const int*)d_in[4];
  const int*   neg_src = (const int*)d_in[5];
  const int*   neg_dst = (const int*)d_in[6];
  const float* Ws0 = (const float*)d_in[7],  *Wn0 = (const float*)d_in[8],  *b0 = (const float*)d_in[9];
  const float* Ws1 = (const float*)d_in[10], *Wn1 = (const float*)d_in[11], *b1 = (const float*)d_in[12];
  const float* Ws2 = (const float*)d_in[13], *Wn2 = (const float*)d_in[14], *b2 = (const float*)d_in[15];
  const float* Wp0 = (const float*)d_in[16], *bp0 = (const float*)d_in[17];
  const float* Wp1 = (const float*)d_in[18], *bp1 = (const float*)d_in[19];
  const float* Wp2 = (const float*)d_in[20], *bp2 = (const float*)d_in[21];
  const int N = in_sizes[0] / D;
  const int E = in_sizes[1];
  const int P = in_sizes[3];
  float* outp = (float*)d_out;

  char* ws = (char*)d_ws;
  size_t off = 0;
  auto alloc = [&](size_t bytes) -> void* {
    void* p = ws + off;
    off += (bytes + 255) & ~(size_t)255;
    return p;
  };
  ushort* xb    = (ushort*)alloc((size_t)N * D * 2);
  ushort* h1    = (ushort*)alloc((size_t)N * D * 2);
  ushort* h2    = (ushort*)alloc((size_t)N * D * 2);
  ushort* BpL0  = (ushort*)alloc(256 * D * 2);
  ushort* BpL1  = (ushort*)alloc(256 * D * 2);
  ushort* BpL2  = (ushort*)alloc(256 * D * 2);
  ushort* BpP0  = (ushort*)alloc(128 * D * 2);
  ushort* BpP1  = (ushort*)alloc(128 * D * 2);
  int*    deg    = (int*)alloc((size_t)N * 4);
  int*    rowptr = (int*)alloc((size_t)(N + 1) * 4);
  int*    cursor = (int*)alloc((size_t)N * 4);
  int*    part   = (int*)alloc(4096);
  int*    csrc   = (int*)alloc((size_t)E * 4);
  (void)ws_size; (void)n_in; (void)out_size;

  const float pscale = 8.0f / (float)N;
  const int CB = 96;                           // blocks per part
  const int CE = (E + CB - 1) / CB;            // edges per chunk

  // --- CSR build (XCD-partitioned) ---
  hipMemsetAsync(deg, 0, (size_t)N * 4, stream);
  k_degree_p<<<8 * CB, 256, 0, stream>>>(dst, E, deg, pscale, CE);
  int nb = (N + SCAN_CHUNK - 1) / SCAN_CHUNK;
  k_scan_partial<<<nb, SCAN_T, 0, stream>>>(deg, N, part);
  k_scan_part_ex<<<1, 1024, 0, stream>>>(part, nb);
  k_scan_final<<<nb, SCAN_T, 0, stream>>>(deg, N, part, rowptr, cursor, E);
  k_fill_p<<<8 * CB, 256, 0, stream>>>(src, dst, E, cursor, csrc, pscale, CE);

  // --- fused conversion + weight packing (one launch) ---
  int n8 = N * D / 8;
  int cb = (n8 + 255) / 256;
  k_conv_pack<<<cb + 512, 256, 0, stream>>>(x, xb, n8, cb,
                                            Ws0, Wn0, Ws1, Wn1, Ws2, Wn2, Wp0, Wp1,
                                            BpL0, BpL1, BpL2, BpP0, BpP1);

  int gemb = (N + 31) / 32;
  k_sage_fused<<<gemb, 128, 0, stream>>>(xb, rowptr, csrc, BpL0, b0, h1, N, 1);
  k_sage_fused<<<gemb, 128, 0, stream>>>(h1, rowptr, csrc, BpL1, b1, h2, N, 1);
  k_sage_fused<<<gemb, 128, 0, stream>>>(h2, rowptr, csrc, BpL2, b2, xb, N, 0);

  int pb = (P + 63) / 64;
  k_predict_mfma<<<2 * pb, 256, 0, stream>>>(xb, pos_src, pos_dst, neg_src, neg_dst,
                                             BpP0, bp0, BpP1, bp1, Wp2, bp2, outp, P, pb);
}

// Round 7
// 435.658 us; speedup vs baseline: 1.0353x; 1.0137x over previous
//
#include <hip/hip_runtime.h>
#include <cstdint>
#include <cstddef>
#include <cmath>

#define D 128

typedef short bf16x8 __attribute__((ext_vector_type(8)));
typedef float f32x4 __attribute__((ext_vector_type(4)));

__device__ __forceinline__ ushort f2b(float f) {
  uint x = __float_as_uint(f);
  uint r = ((x >> 16) & 1u) + 0x7fffu;   // round-to-nearest-even
  return (ushort)((x + r) >> 16);
}
__device__ __forceinline__ float b2f(ushort u) {
  return __uint_as_float(((uint)u) << 16);
}

// global -> LDS direct DMA, 16B per lane; HW writes lane l at lds_base + l*16
__device__ __forceinline__ void gl2lds16(const void* g, void* l) {
  __builtin_amdgcn_global_load_lds(
      (__attribute__((address_space(1))) void*)const_cast<void*>(g),
      (__attribute__((address_space(3))) void*)l, 16, 0, 0);
}

// ========== fused CSR degree (XCD-partitioned) + fp32->bf16 conv + pack ======
// blocks [0,768): degree pass; [768,768+cb): x conversion; rest: weight pack.
// Degree blocks keep blockIdx&7 == XCD round-robin mapping (appended blocks
// don't disturb it). Conv/pack is independent of the edge pass -> overlaps.
__global__ __launch_bounds__(256) void k_degree_conv(
    const int* __restrict__ dst, int E, int* __restrict__ deg, float scale, int CE,
    const float* __restrict__ in, ushort* __restrict__ outx, int n8, int cb,
    const float* __restrict__ Ws0, const float* __restrict__ Wn0,
    const float* __restrict__ Ws1, const float* __restrict__ Wn1,
    const float* __restrict__ Ws2, const float* __restrict__ Wn2,
    const float* __restrict__ Wp0, const float* __restrict__ Wp1,
    ushort* __restrict__ BpL0, ushort* __restrict__ BpL1, ushort* __restrict__ BpL2,
    ushort* __restrict__ BpP0, ushort* __restrict__ BpP1) {
  int b = blockIdx.x;
  if (b < 768) {
    int part = b & 7, chunk = b >> 3;
    long base = (long)chunk * CE;
    for (int i = threadIdx.x; i < CE; i += 256) {
      long e = base + i;
      if (e < E) {
        int d = dst[e];
        int p = (int)((float)d * scale); if (p > 7) p = 7;
        if (p == part) atomicAdd(&deg[d], 1);
      }
    }
    return;
  }
  int b2 = b - 768;
  if (b2 < cb) {
    int i = b2 * 256 + threadIdx.x;
    if (i >= n8) return;
    float4 a = ((const float4*)in)[i * 2];
    float4 c = ((const float4*)in)[i * 2 + 1];
    ushort4 o0 = {f2b(a.x), f2b(a.y), f2b(a.z), f2b(a.w)};
    ushort4 o1 = {f2b(c.x), f2b(c.y), f2b(c.z), f2b(c.w)};
    ((ushort4*)outx)[i * 2] = o0;
    ((ushort4*)outx)[i * 2 + 1] = o1;
    return;
  }
  int o = (b2 - cb) * 256 + threadIdx.x;   // total 131072
  const float *W0, *W1; ushort* outp; int rel;
  if (o < 32768)       { W0 = Ws0; W1 = Wn0; outp = BpL0; rel = o; }
  else if (o < 65536)  { W0 = Ws1; W1 = Wn1; outp = BpL1; rel = o - 32768; }
  else if (o < 98304)  { W0 = Ws2; W1 = Wn2; outp = BpL2; rel = o - 65536; }
  else if (o < 114688) { W0 = Wp0; W1 = Wp0; outp = BpP0; rel = o - 98304; }
  else                 { W0 = Wp1; W1 = Wp1; outp = BpP1; rel = o - 114688; }
  int j = rel & 7, lane = (rel >> 3) & 63, t = (rel >> 9) & 7, ks = rel >> 12;
  int k = ks * 32 + ((lane >> 4) * 8) + j;
  int n = t * 16 + (lane & 15);
  const float* W = (k < 128) ? W0 : W1;
  int kk = (k < 128) ? k : k - 128;
  outp[rel] = f2b(W[(size_t)kk * D + n]);
}

__global__ __launch_bounds__(256) void k_fill_p(const int* __restrict__ src,
    const int* __restrict__ dst, int E, int* __restrict__ cursor,
    int* __restrict__ csrc, float scale, int CE) {
  int part = blockIdx.x & 7, chunk = blockIdx.x >> 3;
  long base = (long)chunk * CE;
  for (int i = threadIdx.x; i < CE; i += 256) {
    long e = base + i;
    if (e < E) {
      int d = dst[e];
      int p = (int)((float)d * scale); if (p > 7) p = 7;
      if (p == part) {
        int s = src[e];
        int pos = atomicAdd(&cursor[d], 1);
        csrc[pos] = s;
      }
    }
  }
}

#define SCAN_T 256
#define SCAN_E 4
#define SCAN_CHUNK (SCAN_T * SCAN_E)

__global__ void k_scan_partial(const int* __restrict__ deg, int n, int* __restrict__ part) {
  __shared__ int s[SCAN_T];
  int base = blockIdx.x * SCAN_CHUNK;
  int sum = 0;
  for (int i = 0; i < SCAN_E; ++i) {
    int idx = base + (int)threadIdx.x * SCAN_E + i;
    if (idx < n) sum += deg[idx];
  }
  s[threadIdx.x] = sum; __syncthreads();
  for (int ofs = SCAN_T / 2; ofs > 0; ofs >>= 1) {
    if ((int)threadIdx.x < ofs) s[threadIdx.x] += s[threadIdx.x + ofs];
    __syncthreads();
  }
  if (threadIdx.x == 0) part[blockIdx.x] = s[0];
}

// scan_final with self-computed block base (folds the old k_scan_part_ex):
// each block tree-sums part[t] for t < blockIdx.x (raw partial sums).
__global__ void k_scan_final(const int* __restrict__ deg, int n, const int* __restrict__ part,
                             int nb, int* __restrict__ rowptr, int* __restrict__ cursor, int E) {
  __shared__ int s[SCAN_T];
  __shared__ int pbase;
  {
    int v = 0;
    for (int t = (int)threadIdx.x; t < (int)blockIdx.x; t += SCAN_T) v += part[t];
    s[threadIdx.x] = v; __syncthreads();
    for (int ofs = SCAN_T / 2; ofs > 0; ofs >>= 1) {
      if ((int)threadIdx.x < ofs) s[threadIdx.x] += s[threadIdx.x + ofs];
      __syncthreads();
    }
    if (threadIdx.x == 0) pbase = s[0];
    __syncthreads();
  }
  int base = blockIdx.x * SCAN_CHUNK;
  int v[SCAN_E]; int local = 0;
  for (int i = 0; i < SCAN_E; ++i) {
    int idx = base + (int)threadIdx.x * SCAN_E + i;
    v[i] = (idx < n) ? deg[idx] : 0;
    local += v[i];
  }
  s[threadIdx.x] = local; __syncthreads();
  for (int ofs = 1; ofs < SCAN_T; ofs <<= 1) {
    int t = ((int)threadIdx.x >= ofs) ? s[threadIdx.x - ofs] : 0;
    __syncthreads();
    s[threadIdx.x] += t;
    __syncthreads();
  }
  int run = pbase + s[threadIdx.x] - local;  // exclusive prefix
  for (int i = 0; i < SCAN_E; ++i) {
    int idx = base + (int)threadIdx.x * SCAN_E + i;
    if (idx < n) { rowptr[idx] = run; cursor[idx] = run; }
    run += v[i];
  }
  if (blockIdx.x == 0 && threadIdx.x == 0) rowptr[n] = E;
}

// ======================= fused aggregate + SAGE GEMM =======================
// r6 structure unchanged (62.5us measured): 2 independent wave-tiles of 16
// rows, unroll-4 unconditional 16-load clusters, pipelined clamped offset
// shuffles, {0,1}-weight fmac, wave-local smean handoff.
#define SMS 136
__global__ __launch_bounds__(128, 4) void k_sage_fused(
    const ushort* __restrict__ A, const int* __restrict__ rowptr,
    const int* __restrict__ csrc, const ushort* __restrict__ Bp,
    const float* __restrict__ bias, ushort* __restrict__ out, int N, int do_relu) {
  __shared__ __align__(16) ushort smean[2][16][SMS];   // 8704 B
  int tid = threadIdx.x, wave = tid >> 6, lane = tid & 63;
  int m = lane & 15, kg = lane >> 4;        // MFMA roles
  int g = kg, sub = m;                      // gather roles: 4 groups of 16
  int gb = g << 4;                          // group base lane
  int row0 = (blockIdx.x * 2 + wave) * 16;  // this wave's 16-row tile
  uint hbo = (uint)(sub * 16);              // byte offset of this lane's 16B slice

  // ---- phase A: rowptr + edge-index prefetch ----
  int node0 = row0 + g * 4;
  int rpv = 0;
  if (sub < 5) { int ix = node0 + sub; if (ix > N) ix = N; rpv = rowptr[ix]; }
  int beg[4], dgf[4], dd[4];
  #pragma unroll
  for (int j = 0; j < 4; ++j) {
    beg[j] = __shfl(rpv, gb + j);
    int endj = __shfl(rpv, gb + j + 1);
    dgf[j] = endj - beg[j];
    dd[j] = dgf[j] < 16 ? dgf[j] : 16;
  }
  int idxv[4];
  #pragma unroll
  for (int j = 0; j < 4; ++j) {
    int i = beg[j] + sub;
    idxv[j] = (sub < dgf[j]) ? csrc[i] : 0;
  }

  // ---- phase B: unroll-4 gather, unconditional 16-load clusters ----
  float f[4][8];
  #pragma unroll
  for (int j = 0; j < 4; ++j)
    #pragma unroll
    for (int q = 0; q < 8; ++q) f[j][q] = 0.f;

  int maxdd = dd[0];
  if (dd[1] > maxdd) maxdd = dd[1];
  if (dd[2] > maxdd) maxdd = dd[2];
  if (dd[3] > maxdd) maxdd = dd[3];

  uint off[4][4];
  #pragma unroll
  for (int j = 0; j < 4; ++j)
    #pragma unroll
    for (int k = 0; k < 4; ++k)
      off[j][k] = hbo + ((uint)__shfl(idxv[j], gb + k) << 8);

  #pragma unroll 1
  for (int e = 0; e < maxdd; e += 4) {
    bf16x8 r[4][4];
    #pragma unroll
    for (int j = 0; j < 4; ++j)
      #pragma unroll
      for (int k = 0; k < 4; ++k)
        r[j][k] = *(const bf16x8*)((const char*)A + off[j][k]);
    __builtin_amdgcn_sched_barrier(0);
    #pragma unroll
    for (int j = 0; j < 4; ++j)
      #pragma unroll
      for (int k = 0; k < 4; ++k) {
        int sl = e + 4 + k; sl = (sl > 15) ? 15 : sl;
        off[j][k] = hbo + ((uint)__shfl(idxv[j], gb + sl) << 8);
      }
    __builtin_amdgcn_sched_barrier(0);
    #pragma unroll
    for (int j = 0; j < 4; ++j) {
      #pragma unroll
      for (int k = 0; k < 4; ++k) {
        float w = (e + k < dd[j]) ? 1.0f : 0.0f;
        #pragma unroll
        for (int q = 0; q < 8; ++q) f[j][q] += w * b2f((ushort)r[j][k][q]);
      }
    }
  }
  // rare deg>16 tail
  #pragma unroll
  for (int j = 0; j < 4; ++j) {
    int endj = beg[j] + dgf[j];
    for (int i = beg[j] + 16; i < endj; ++i) {
      int s = csrc[i];
      bf16x8 v = *(const bf16x8*)((const char*)A + (hbo + ((uint)s << 8)));
      #pragma unroll
      for (int q = 0; q < 8; ++q) f[j][q] += b2f((ushort)v[q]);
    }
  }
  #pragma unroll
  for (int j = 0; j < 4; ++j) {
    float inv = (dgf[j] > 0) ? (1.0f / (float)dgf[j]) : 0.0f;
    bf16x8 o;
    #pragma unroll
    for (int q = 0; q < 8; ++q) o[q] = (short)f2b(f[j][q] * inv);
    *(bf16x8*)&smean[wave][g * 4 + j][sub * 8] = o;
  }
  asm volatile("s_waitcnt lgkmcnt(0)" ::: "memory");
  __builtin_amdgcn_sched_barrier(0);

  // ---- MFMA phase ----
  int ar = row0 + m; if (ar >= N) ar = N - 1;
  const ushort* a_self = A + (size_t)ar * D + kg * 8;
  f32x4 acc[8];
  #pragma unroll
  for (int t = 0; t < 8; ++t) acc[t] = f32x4{0.f, 0.f, 0.f, 0.f};
  #pragma unroll
  for (int ks = 0; ks < 8; ++ks) {
    bf16x8 af = (ks < 4) ? *(const bf16x8*)(a_self + ks * 32)
                         : *(const bf16x8*)&smean[wave][m][(ks - 4) * 32 + kg * 8];
    const ushort* bb = Bp + (size_t)ks * 4096 + lane * 8;
    #pragma unroll
    for (int t = 0; t < 8; ++t)
      acc[t] = __builtin_amdgcn_mfma_f32_16x16x32_bf16(af, *(const bf16x8*)(bb + t * 512), acc[t], 0, 0, 0);
  }
  #pragma unroll
  for (int t = 0; t < 8; ++t) {
    int c = t * 16 + m;
    float bv = bias[c];
    #pragma unroll
    for (int i = 0; i < 4; ++i) {
      int r = row0 + kg * 4 + i;
      float v = acc[t][i] + bv;
      if (do_relu) v = fmaxf(v, 0.f);
      if (r < N) out[(size_t)r * D + c] = f2b(v);
    }
  }
}

// ======================= fused predictor MLP (DMA-staged gathers) ==============
// Per wave (16 pairs): 8 global_load_lds stage all hs+hd rows (8KB) into a
// wave slab with ZERO data-VGPR cost -- full gather depth in flight at once.
// m97-verified pattern: stage -> __syncthreads (compiler drains vmcnt(0)) ->
// ds_read. Row-stride-256B reads would be 16-way bank-conflicted, so the
// SOURCE global address is pre-swizzled (slice ^= row&7) and reads use the
// same XOR (rule: linear dest + inverse-swz source + swz read). z1p overlays
// the consumed hs region (wave-private, DS ops in-order per wave).
// LDS 32KB/block -> 5 blocks/CU = 20 waves/CU.
__global__ __launch_bounds__(256, 5) void k_predict_mfma(
    const ushort* __restrict__ h,
    const int* __restrict__ ps, const int* __restrict__ pd,
    const int* __restrict__ ns, const int* __restrict__ nd,
    const ushort* __restrict__ Bp0, const float* __restrict__ bp0,
    const ushort* __restrict__ Bp1, const float* __restrict__ bp1,
    const float* __restrict__ Wp2, const float* __restrict__ bp2,
    float* __restrict__ outp, int P, int pb) {
  __shared__ __align__(1024) ushort slab[4][4096];  // 8KB/wave: hs @0, hd @4KB
  int bi = blockIdx.x;
  const int* sidx; const int* didx; float* op;
  if (bi >= pb) { sidx = ns; didx = nd; op = outp + P; bi -= pb; }
  else          { sidx = ps; didx = pd; op = outp; }
  int tid = threadIdx.x;
  int wave = tid >> 6, lane = tid & 63;
  int m = lane & 15, kg = lane >> 4;
  int pair0 = bi * 64 + wave * 16;
  int prow = pair0 + m; int pr = (prow < P) ? prow : P - 1;
  int si = sidx[pr], di = didx[pr];    // lane m holds pair m (kg-duplicated)
  char* sl = (char*)&slab[wave][0];

  // ---- stage: instr q covers rows q*4+(lane>>4); lane l writes LDS at +l*16.
  // source slice = (l&15) ^ (row&7)  => LDS slot c of row r holds slice c^(r&7)
  {
    int rsub = lane >> 4;
    #pragma unroll
    for (int q = 0; q < 4; ++q) {
      int rr = q * 4 + rsub;
      int ir = __shfl(si, rr);
      const char* g = (const char*)h + ((size_t)(uint)ir << 8)
                      + (uint)((((lane & 15) ^ (rr & 7)) << 4));
      gl2lds16(g, sl + (q << 10));
    }
    #pragma unroll
    for (int q = 0; q < 4; ++q) {
      int rr = q * 4 + rsub;
      int ir = __shfl(di, rr);
      const char* g = (const char*)h + ((size_t)(uint)ir << 8)
                      + (uint)((((lane & 15) ^ (rr & 7)) << 4));
      gl2lds16(g, sl + 4096 + (q << 10));
    }
  }
  __syncthreads();   // compiler drains vmcnt(0) before barrier (m97 semantics)

  f32x4 acc[8];
  #pragma unroll
  for (int t = 0; t < 8; ++t) acc[t] = f32x4{0.f, 0.f, 0.f, 0.f};
  // ---- GEMM1: z = hs*hd ; acc = z @ Wp0 (swizzled LDS reads) ----
  #pragma unroll
  for (int ks = 0; ks < 4; ++ks) {
    int slot = (ks * 4 + kg) ^ (m & 7);
    const char* rbase = sl + m * 256 + slot * 16;
    bf16x8 as8 = *(const bf16x8*)rbase;
    bf16x8 ad8 = *(const bf16x8*)(rbase + 4096);
    bf16x8 af;
    #pragma unroll
    for (int j = 0; j < 8; ++j) {
      float p = b2f((ushort)as8[j]) * b2f((ushort)ad8[j]);
      af[j] = (short)f2b(p);
    }
    const ushort* bb = Bp0 + (size_t)ks * 4096 + lane * 8;
    #pragma unroll
    for (int t = 0; t < 8; ++t)
      acc[t] = __builtin_amdgcn_mfma_f32_16x16x32_bf16(af, *(const bf16x8*)(bb + t * 512), acc[t], 0, 0, 0);
  }
  // ---- epilogue1: relu(acc + bp0) -> z1p (overlays consumed hs region) ----
  ushort* zp = (ushort*)sl;
  #pragma unroll
  for (int t = 0; t < 8; ++t) {
    int c = t * 16 + m;
    float bv = bp0[c];
    int ks2 = c >> 5, kg2 = (c >> 3) & 3, j2 = c & 7;
    #pragma unroll
    for (int i = 0; i < 4; ++i) {
      float v = fmaxf(acc[t][i] + bv, 0.f);
      int l2 = kg2 * 16 + kg * 4 + i;     // consumer lane
      zp[(ks2 * 64 + l2) * 8 + j2] = f2b(v);
    }
  }
  // wave-local handoff (slab written and read by THIS wave only)
  asm volatile("s_waitcnt lgkmcnt(0)" ::: "memory");
  __builtin_amdgcn_sched_barrier(0);
  // ---- GEMM2: acc = z1 @ Wp1 ----
  #pragma unroll
  for (int t = 0; t < 8; ++t) acc[t] = f32x4{0.f, 0.f, 0.f, 0.f};
  #pragma unroll
  for (int ks = 0; ks < 4; ++ks) {
    bf16x8 af = *(const bf16x8*)(zp + (ks * 64 + lane) * 8);
    const ushort* bb = Bp1 + (size_t)ks * 4096 + lane * 8;
    #pragma unroll
    for (int t = 0; t < 8; ++t)
      acc[t] = __builtin_amdgcn_mfma_f32_16x16x32_bf16(af, *(const bf16x8*)(bb + t * 512), acc[t], 0, 0, 0);
  }
  // ---- final: z2 = relu(acc + bp1); logits = z2 @ Wp2 + bp2; sigmoid ----
  float p0[4] = {0.f, 0.f, 0.f, 0.f}, p1[4] = {0.f, 0.f, 0.f, 0.f};
  #pragma unroll
  for (int t = 0; t < 8; ++t) {
    int c = t * 16 + m;
    float bv = bp1[c];
    float wa = Wp2[(size_t)c * 2], wb = Wp2[(size_t)c * 2 + 1];
    #pragma unroll
    for (int i = 0; i < 4; ++i) {
      float z = fmaxf(acc[t][i] + bv, 0.f);
      p0[i] += z * wa;
      p1[i] += z * wb;
    }
  }
  #pragma unroll
  for (int msk = 1; msk <= 8; msk <<= 1) {
    #pragma unroll
    for (int i = 0; i < 4; ++i) {
      p0[i] += __shfl_xor(p0[i], msk);
      p1[i] += __shfl_xor(p1[i], msk);
    }
  }
  if (m == 0) {
    float c0 = bp2[0], c1 = bp2[1];
    #pragma unroll
    for (int i = 0; i < 4; ++i) {
      int r = pair0 + kg * 4 + i;
      if (r < P) {
        float l0 = p0[i] + c0, l1 = p1[i] + c1;
        op[r] = 1.0f / (1.0f + expf(l0 - l1));
      }
    }
  }
}

// ======================= launch =======================
extern "C" void kernel_launch(void* const* d_in, const int* in_sizes, int n_in,
                              void* d_out, int out_size, void* d_ws, size_t ws_size,
                              hipStream_t stream) {
  const float* x       = (const float*)d_in[0];
  const int*   src     = (const int*)d_in[1];
  const int*   dst     = (const int*)d_in[2];
  const int*   pos_src = (const int*)d_in[3];
  const int*   pos_dst = (const int*)d_in[4];
  const int*   neg_src = (const int*)d_in[5];
  const int*   neg_dst = (const int*)d_in[6];
  const float* Ws0 = (const float*)d_in[7],  *Wn0 = (const float*)d_in[8],  *b0 = (const float*)d_in[9];
  const float* Ws1 = (const float*)d_in[10], *Wn1 = (const float*)d_in[11], *b1 = (const float*)d_in[12];
  const float* Ws2 = (const float*)d_in[13], *Wn2 = (const float*)d_in[14], *b2 = (const float*)d_in[15];
  const float* Wp0 = (const float*)d_in[16], *bp0 = (const float*)d_in[17];
  const float* Wp1 = (const float*)d_in[18], *bp1 = (const float*)d_in[19];
  const float* Wp2 = (const float*)d_in[20], *bp2 = (const float*)d_in[21];
  const int N = in_sizes[0] / D;
  const int E = in_sizes[1];
  const int P = in_sizes[3];
  float* outp = (float*)d_out;

  char* ws = (char*)d_ws;
  size_t off = 0;
  auto alloc = [&](size_t bytes) -> void* {
    void* p = ws + off;
    off += (bytes + 255) & ~(size_t)255;
    return p;
  };
  ushort* xb    = (ushort*)alloc((size_t)N * D * 2);
  ushort* h1    = (ushort*)alloc((size_t)N * D * 2);
  ushort* h2    = (ushort*)alloc((size_t)N * D * 2);
  ushort* BpL0  = (ushort*)alloc(256 * D * 2);
  ushort* BpL1  = (ushort*)alloc(256 * D * 2);
  ushort* BpL2  = (ushort*)alloc(256 * D * 2);
  ushort* BpP0  = (ushort*)alloc(128 * D * 2);
  ushort* BpP1  = (ushort*)alloc(128 * D * 2);
  int*    deg    = (int*)alloc((size_t)N * 4);
  int*    rowptr = (int*)alloc((size_t)(N + 1) * 4);
  int*    cursor = (int*)alloc((size_t)N * 4);
  int*    part   = (int*)alloc(4096);
  int*    csrc   = (int*)alloc((size_t)E * 4);
  (void)ws_size; (void)n_in; (void)out_size;

  const float pscale = 8.0f / (float)N;
  const int CB = 96;                           // blocks per part
  const int CE = (E + CB - 1) / CB;            // edges per chunk

  // --- CSR degree + conv/pack (fused, independent halves) ---
  hipMemsetAsync(deg, 0, (size_t)N * 4, stream);
  int n8 = N * D / 8;
  int cb = (n8 + 255) / 256;
  k_degree_conv<<<8 * CB + cb + 512, 256, 0, stream>>>(
      dst, E, deg, pscale, CE,
      x, xb, n8, cb,
      Ws0, Wn0, Ws1, Wn1, Ws2, Wn2, Wp0, Wp1,
      BpL0, BpL1, BpL2, BpP0, BpP1);

  int nb = (N + SCAN_CHUNK - 1) / SCAN_CHUNK;
  k_scan_partial<<<nb, SCAN_T, 0, stream>>>(deg, N, part);
  k_scan_final<<<nb, SCAN_T, 0, stream>>>(deg, N, part, nb, rowptr, cursor, E);
  k_fill_p<<<8 * CB, 256, 0, stream>>>(src, dst, E, cursor, csrc, pscale, CE);

  int gemb = (N + 31) / 32;
  k_sage_fused<<<gemb, 128, 0, stream>>>(xb, rowptr, csrc, BpL0, b0, h1, N, 1);
  k_sage_fused<<<gemb, 128, 0, stream>>>(h1, rowptr, csrc, BpL1, b1, h2, N, 1);
  k_sage_fused<<<gemb, 128, 0, stream>>>(h2, rowptr, csrc, BpL2, b2, xb, N, 0);

  int pb = (P + 63) / 64;
  k_predict_mfma<<<2 * pb, 256, 0, stream>>>(xb, pos_src, pos_dst, neg_src, neg_dst,
                                             BpP0, bp0, BpP1, bp1, Wp2, bp2, outp, P, pb);
}